// Round 12
// baseline (5411.669 us; speedup 1.0000x reference)
//
#include <hip/hip_runtime.h>
#include <math.h>

#define NB   16
#define TE   256
#define TD   200
#define EE   512
#define ATT  128
#define PREN 256
#define HH   1024
#define NMEL 80
#define NLOC 32
#define KWW  31
#define PADW 15

// workspace offsets (float slots)
#define OFF_X2H  0                          // [TD][NB][128] u32 (256 fp16)
#define OFF_PE   (OFF_X2H + TD*NB*128)      // [NB][TE][ATT] f32
#define OFF_ENR  (OFF_PE + NB*TE*ATT)       // [NB][16][6] f4 recs {3 f32, tag}
#define OFF_CTR  (OFF_ENR + NB*16*6*4)      // [NB][128] u32x4 recs {2 u32, tag, 0}
#define OFF_H1R  (OFF_CTR + NB*128*4)       // [NB][256] u32x4 recs {h01,h23,tag,0}
#define OFF_H2R  (OFF_H1R + NB*256*4)       // [NB][256] f4 recs {h01,h23,tag,0}
#define OFF_QVR  (OFF_H2R + NB*256*4)       // [NB][16][2] f4 recs

// dynamic LDS (u32 counts): fp16-packed weight slices (round-10 layout)
#define LW0X_U32 (12*128)
#define LW0C_U32 (12*256)
#define LW1_U32  (12*512)
#define DYN_BYTES ((LW0X_U32 + LW0C_U32 + LW1_U32)*4)

typedef float f4 __attribute__((ext_vector_type(4)));
typedef unsigned int u32x4 __attribute__((ext_vector_type(4)));
typedef _Float16 h2t __attribute__((ext_vector_type(2)));

__device__ __forceinline__ float sigmf(float x) { return 1.0f / (1.0f + expf(-x)); }
__device__ __forceinline__ float dot4(f4 a, f4 b) {
  return a.x*b.x + a.y*b.y + a.z*b.z + a.w*b.w;
}
__device__ __forceinline__ float red32(float v) {
  v += __shfl_down(v, 16, 32); v += __shfl_down(v, 8, 32);
  v += __shfl_down(v, 4, 32);  v += __shfl_down(v, 2, 32);
  v += __shfl_down(v, 1, 32);
  return v;
}
__device__ __forceinline__ float red64(float v) {
  v += __shfl_down(v, 32); v += __shfl_down(v, 16); v += __shfl_down(v, 8);
  v += __shfl_down(v, 4);  v += __shfl_down(v, 2);  v += __shfl_down(v, 1);
  return v;
}
__device__ __forceinline__ float fdot2(unsigned a, unsigned b, float c) {
  return __builtin_amdgcn_fdot2(__builtin_bit_cast(h2t, a),
                                __builtin_bit_cast(h2t, b), c, false);
}
__device__ __forceinline__ unsigned pkh(float a, float b) {
  h2t h; h.x = (_Float16)a; h.y = (_Float16)b;
  return __builtin_bit_cast(unsigned, h);
}
__device__ __forceinline__ float hlo(unsigned u) {
  return (float)__builtin_bit_cast(h2t, u).x;
}
__device__ __forceinline__ float hhi(unsigned u) {
  return (float)__builtin_bit_cast(h2t, u).y;
}

// ---- LLC-coherent (L1+L2 bypass) accessors ----
__device__ __forceinline__ unsigned ld_cg_u32(const unsigned* p) {
  unsigned r;
  asm volatile("global_load_dword %0, %1, off sc0 sc1\n\ts_waitcnt vmcnt(0)"
               : "=v"(r) : "v"(p) : "memory");
  return r;
}
__device__ __forceinline__ void st_cg_u32(unsigned* p, unsigned v) {
  asm volatile("global_store_dword %0, %1, off sc0 sc1" :: "v"(p), "v"(v) : "memory");
}
__device__ __forceinline__ f4 ld_cg_f4(const f4* p) {
  f4 r;
  asm volatile("global_load_dwordx4 %0, %1, off sc0 sc1\n\ts_waitcnt vmcnt(0)"
               : "=v"(r) : "v"(p) : "memory");
  return r;
}
__device__ __forceinline__ void st_cg_f4(f4* p, f4 v) {
  asm volatile("global_store_dwordx4 %0, %1, off sc0 sc1" :: "v"(p), "v"(v) : "memory");
}
__device__ __forceinline__ u32x4 ld_cg_u4(const void* p) {
  u32x4 r;
  asm volatile("global_load_dwordx4 %0, %1, off sc0 sc1\n\ts_waitcnt vmcnt(0)"
               : "=v"(r) : "v"(p) : "memory");
  return r;
}
__device__ __forceinline__ void st_cg_u4(void* p, u32x4 v) {
  asm volatile("global_store_dwordx4 %0, %1, off sc0 sc1" :: "v"(p), "v"(v) : "memory");
}
__device__ __forceinline__ void ld4u(u32x4& a, u32x4& b, u32x4& c, u32x4& d,
                                     const void* pa, const void* pb,
                                     const void* pc, const void* pd) {
  asm volatile(
    "global_load_dwordx4 %0, %4, off sc0 sc1\n\t"
    "global_load_dwordx4 %1, %5, off sc0 sc1\n\t"
    "global_load_dwordx4 %2, %6, off sc0 sc1\n\t"
    "global_load_dwordx4 %3, %7, off sc0 sc1\n\t"
    "s_waitcnt vmcnt(0)"
    : "=&v"(a), "=&v"(b), "=&v"(c), "=&v"(d)
    : "v"(pa), "v"(pb), "v"(pc), "v"(pd) : "memory");
}

// ---------------- init: zero ALL tagged record regions ----------------
__global__ void k_init(float* __restrict__ ws) {
  const int gid = blockIdx.x * 256 + threadIdx.x;
  f4* enr = (f4*)(ws + OFF_ENR);
  u32x4* ctr = (u32x4*)(ws + OFF_CTR);
  u32x4* h1r = (u32x4*)(ws + OFF_H1R);
  f4* h2r = (f4*)(ws + OFF_H2R);
  f4* qvr = (f4*)(ws + OFF_QVR);
  const f4 z = (f4){0.f, 0.f, 0.f, 0.f};
  const u32x4 zu = (u32x4){0u, 0u, 0u, 0u};
  for (int i = gid; i < NB*16*6; i += 32*256) st_cg_f4(enr + i, z);
  for (int i = gid; i < NB*128; i += 32*256) st_cg_u4(ctr + i, zu);
  for (int i = gid; i < NB*256; i += 32*256) st_cg_u4(h1r + i, zu);
  for (int i = gid; i < NB*256; i += 32*256) st_cg_f4(h2r + i, z);
  for (int i = gid; i < NB*32; i += 32*256) st_cg_f4(qvr + i, z);
}

// ---------------- prenet (fp16 output) ----------------
__global__ void k_prenet(const float* __restrict__ mels,
                         const float* __restrict__ w1,
                         const float* __restrict__ w2,
                         float* __restrict__ ws) {
  const int t = blockIdx.x >> 4;
  const int b = blockIdx.x & 15;
  const int j = threadIdx.x;
  __shared__ float s_in[NMEL];
  __shared__ float s_x1[PREN];
  if (j < NMEL) s_in[j] = (t == 0) ? 0.0f : mels[(b*TD + (t-1))*NMEL + j];
  __syncthreads();
  float a1 = 0.0f;
  #pragma unroll 8
  for (int k = 0; k < NMEL; ++k) a1 += s_in[k] * w1[j*NMEL + k];
  s_x1[j] = fmaxf(a1, 0.0f);
  __syncthreads();
  float a2 = 0.0f;
  #pragma unroll 8
  for (int k = 0; k < PREN; ++k) a2 += s_x1[k] * w2[j*PREN + k];
  ((_Float16*)(ws + OFF_X2H))[((size_t)t*NB + b)*256 + j] = (_Float16)fmaxf(a2, 0.0f);
}

// ---------------- processed encoder ----------------
__global__ void k_procenc(const float* __restrict__ enc,
                          const float* __restrict__ w,
                          float* __restrict__ pe) {
  const int bt = blockIdx.x;
  const int a = threadIdx.x;
  __shared__ float s_e[EE];
  for (int k = a; k < EE; k += 128) s_e[k] = enc[bt*EE + k];
  __syncthreads();
  float acc = 0.0f;
  #pragma unroll 8
  for (int k = 0; k < EE; ++k) acc += s_e[k] * w[a*EE + k];
  pe[bt*ATT + a] = acc;
}

// ---------------- main decoder loop (pure dataflow, zero barriers) ----------------
__global__ void __launch_bounds__(512, 1) k_main(
    const float* __restrict__ enc,
    const float* __restrict__ lstm_proj_w,
    const float* __restrict__ loc_conv_w,
    const float* __restrict__ loc_conv_b,
    const float* __restrict__ loc_dense_w,
    const float* __restrict__ loc_dense_b,
    const float* __restrict__ e_w,
    const float* __restrict__ e_b,
    const float* __restrict__ w_ih0,
    const float* __restrict__ b_ih0,
    const float* __restrict__ b_hh0,
    const float* __restrict__ w_ih1,
    const float* __restrict__ b_ih1,
    const float* __restrict__ b_hh1,
    const float* __restrict__ proj_w,
    const float* __restrict__ proj_b,
    const float* __restrict__ stop_w,
    const float* __restrict__ stop_b,
    const int*   __restrict__ text_len,
    float* __restrict__ ws,
    float* __restrict__ out) {
  const int bid = blockIdx.x;
  const int tid = threadIdx.x;

  const unsigned* x2h = (const unsigned*)(ws + OFF_X2H);
  float* pe  = ws + OFF_PE;
  f4* en_rec = (f4*)(ws + OFF_ENR);
  u32x4* ct_rec = (u32x4*)(ws + OFF_CTR);
  u32x4* h1_rec = (u32x4*)(ws + OFF_H1R);
  f4* h2_rec = (f4*)(ws + OFF_H2R);
  f4* qv_rec = (f4*)(ws + OFF_QVR);

  __shared__ __align__(16) float s_ldw[NLOC*ATT];   // loc_dense_w^T [c][a] f32
  __shared__ float s_awcf[TE];                      // local cumulative attn
  __shared__ float s_loc[16*33];
  __shared__ float s_red[16];
  __shared__ float s_en[256];
  __shared__ float s_aw[256];
  __shared__ float s_entmp[16];
  __shared__ float s_qtmp[8];
  __shared__ float s_ctmp[32];
  __shared__ __align__(16) float s_q[ATT];
  __shared__ __align__(16) float s_dec[HH+EE];      // [h2 f32 | ctx f32]
  __shared__ float s_b0[12], s_b1[12];
  extern __shared__ __align__(16) unsigned dynlds_u[];
  unsigned* lw0x = dynlds_u;                 // [12][128] u32
  unsigned* lw0c = lw0x + LW0X_U32;          // [12][256] u32
  unsigned* lw1  = lw0c + LW0C_U32;          // [12][512] u32

  const int b_grp = bid & 15;
  const int sub   = bid >> 4;
  const int h0    = bid * 4;

  // ---- one-time staging ----
  for (int i = tid; i < NLOC*ATT; i += 512) {
    int c = i >> 7, a = i & 127;
    s_ldw[i] = loc_dense_w[a*NLOC + c];
  }
  if (tid < 12) {
    int g = tid >> 2, h = tid & 3;
    int gr = (g == 0 ? 0 : (g == 1 ? 2048 : 3072)) + h0 + h;
    s_b0[tid] = b_ih0[gr] + b_hh0[gr];
    s_b1[tid] = b_ih1[gr] + b_hh1[gr];
  }
  for (int i = tid; i < LW0X_U32; i += 512) {
    int r = i >> 7, c = i & 127;
    int g = r >> 2, h = r & 3;
    int grow = (g == 0 ? 0 : (g == 1 ? 2048 : 3072)) + h0 + h;
    const float* wr = w_ih0 + (size_t)grow*768;
    lw0x[i] = pkh(wr[2*c], wr[2*c+1]);
  }
  for (int i = tid; i < LW0C_U32; i += 512) {
    int r = i >> 8, c = i & 255;
    int g = r >> 2, h = r & 3;
    int grow = (g == 0 ? 0 : (g == 1 ? 2048 : 3072)) + h0 + h;
    const float* wr = w_ih0 + (size_t)grow*768 + 256;
    lw0c[i] = pkh(wr[2*c], wr[2*c+1]);
  }
  for (int i = tid; i < LW1_U32; i += 512) {
    int r = i >> 9, c = i & 511;
    int g = r >> 2, h = r & 3;
    int grow = (g == 0 ? 0 : (g == 1 ? 2048 : 3072)) + h0 + h;
    const float* wr = w_ih1 + (size_t)grow*1024;
    lw1[i] = pkh(wr[2*c], wr[2*c+1]);
  }
  if (tid < 256) s_awcf[tid] = 0.0f;

  const int   lenb = text_len[b_grp];
  const float eb0  = e_b[0];
  // P1 invariants
  const int tl = tid >> 5;
  const int j  = tid & 31;
  float lcw_r[KWW];
  #pragma unroll
  for (int k = 0; k < KWW; ++k) lcw_r[k] = loc_conv_w[j*KWW + k];
  const float lcb_r = loc_conv_b[j];
  const f4 db_r = *(const f4*)(loc_dense_b + 4*j);
  const f4 ew_r = *(const f4*)(e_w + 4*j);
  const f4 pe_r = *(const f4*)(pe + (size_t)(b_grp*TE + sub*16 + tl)*ATT + 4*j);
  const f4 ps_r = pe_r + db_r;
  // P2 invariants
  const int e4i = tid >> 6;
  const int ts  = tid & 63;
  f4 encr[4];
  {
    const f4* enc4 = (const f4*)(enc + (size_t)b_grp*TE*EE);
    #pragma unroll
    for (int i = 0; i < 4; ++i)
      encr[i] = enc4[(size_t)(ts + 64*i)*(EE/4) + sub*8 + e4i];
  }
  // en-poll invariants (tid<96): si = tid/6, rr = tid%6
  const int en_si = tid / 6;
  const int en_rr = tid - en_si*6;
  const f4* en_myrec = en_rec + (b_grp*16 + en_si)*6 + en_rr;
  // P3/P4 mapping
  const int pb = tid >> 5;
  const int kc = tid & 31;
  const u32x4* ct_my = ct_rec + pb*128;      // this thread's ctx recs base
  const u32x4* h1_my = h1_rec + pb*256;      // this thread's h1 recs base
  __syncthreads();

  for (int t = 0; t < TD; ++t) {
    const unsigned tg = (unsigned)(t + 1);
    // ===== P1a: conv from s_awcf + loc_dense pre-term (all-LDS) =====
    f4 pre;
    {
      float cv = lcb_r;
      const int pos = sub*16 + tl;
      #pragma unroll
      for (int k = 0; k < KWW; ++k) {
        const int g = pos - PADW + k;
        const float av = (g >= 0 && g < TE) ? s_awcf[g] : 0.0f;
        cv += av * lcw_r[k];
      }
      s_loc[tl*33 + j] = cv;
      __syncthreads();
      f4 d4 = (f4){0.f, 0.f, 0.f, 0.f};
      #pragma unroll 8
      for (int c = 0; c < NLOC; ++c) {
        const float lv = s_loc[tl*33 + c];
        const f4 w4 = ((const f4*)s_ldw)[c*32 + j];
        d4.x += lv*w4.x; d4.y += lv*w4.y; d4.z += lv*w4.z; d4.w += lv*w4.w;
      }
      pre = ps_r + d4;
    }
    // ===== P1b: poll qv recs (tag==t), energies -> tagged en recs =====
    {
      if (tid < 32) {
        const int src = tid >> 1, r = tid & 1;
        const f4* qp = qv_rec + (b_grp*16 + src)*2 + r;
        f4 v;
        do { v = ld_cg_f4(qp); } while (__float_as_uint(v.z) != (unsigned)t);
        const unsigned u0 = __float_as_uint(v.x), u1 = __float_as_uint(v.y);
        const int base = src*8 + r*4;
        s_q[base+0] = hlo(u0); s_q[base+1] = hhi(u0);
        s_q[base+2] = hlo(u1); s_q[base+3] = hhi(u1);
      }
      __syncthreads();
      const f4 q4 = *(const f4*)(s_q + 4*j);
      float acc = tanhf(pre.x+q4.x)*ew_r.x + tanhf(pre.y+q4.y)*ew_r.y
                + tanhf(pre.z+q4.z)*ew_r.z + tanhf(pre.w+q4.w)*ew_r.w;
      acc = red32(acc);
      if (j == 0) {
        float evv = acc + eb0;
        const int tt = sub*16 + tl;
        if (tt >= lenb) evv = -1e9f;
        s_entmp[tl] = evv;
      }
      __syncthreads();
      if (tid < 6) {
        f4 r = (f4){0.f, 0.f, 0.f, __uint_as_float(tg)};
        const int base = 3*tid;
        r.x = s_entmp[base];
        if (base + 1 < 16) r.y = s_entmp[base+1];
        if (base + 2 < 16) r.z = s_entmp[base+2];
        st_cg_f4(en_rec + (b_grp*16 + sub)*6 + tid, r);
      }
    }
    // ===== P2: {en poll (tid<96)} || {mel shadow (tid 128..319)} =====
    {
      if (tid < 96) {
        f4 v;
        do { v = ld_cg_f4(en_myrec); } while (__float_as_uint(v.w) != tg);
        const int base = en_si*16 + 3*en_rr;
        s_en[base] = v.x;
        if (3*en_rr + 1 < 16) s_en[base+1] = v.y;
        if (3*en_rr + 2 < 16) s_en[base+2] = v.z;
      } else if (t > 0 && tid >= 128 && tid < 320) {
        const int ol = (tid - 128) >> 5, kq = tid & 31;
        const int m = sub*6 + ol;
        if (m < 81) {
          const float* wrow = (m < NMEL) ? (proj_w + (size_t)m*(HH+EE)) : stop_w;
          const f4* w4 = (const f4*)wrow;
          const f4* s4 = (const f4*)s_dec;
          float a2 = 0.0f;
          #pragma unroll
          for (int i = 0; i < 12; ++i) a2 += dot4(s4[kq + 32*i], w4[kq + 32*i]);
          a2 = red32(a2);
          if (kq == 0) {
            if (m < NMEL) out[(b_grp*TD + (t-1))*NMEL + m] = a2 + proj_b[m];
            else          out[NB*TD*NMEL + b_grp*TD + (t-1)] = a2 + stop_b[0];
          }
        }
      }
      __syncthreads();
      // softmax + local awc + ctx -> tagged ctx recs
      float evv = 0.f, p = 0.f;
      if (tid < 256) {
        evv = s_en[tid];
        float m = evv;
        #pragma unroll
        for (int d = 32; d > 0; d >>= 1) m = fmaxf(m, __shfl_xor(m, d));
        if ((tid & 63) == 0) s_red[tid >> 6] = m;
      }
      __syncthreads();
      const float mx = fmaxf(fmaxf(s_red[0], s_red[1]), fmaxf(s_red[2], s_red[3]));
      if (tid < 256) {
        p = expf(evv - mx);
        float sm = p;
        #pragma unroll
        for (int d = 32; d > 0; d >>= 1) sm += __shfl_xor(sm, d);
        if ((tid & 63) == 0) s_red[8 + (tid >> 6)] = sm;
      }
      __syncthreads();
      const float inv = 1.0f / (s_red[8] + s_red[9] + s_red[10] + s_red[11]);
      if (tid < 256) {
        const float aw = p * inv;
        s_aw[tid] = aw;
        s_awcf[tid] += aw;
      }
      __syncthreads();
      f4 a4 = (f4){0.f, 0.f, 0.f, 0.f};
      #pragma unroll
      for (int i = 0; i < 4; ++i) {
        const float awv = s_aw[ts + 64*i];
        a4.x += awv*encr[i].x; a4.y += awv*encr[i].y;
        a4.z += awv*encr[i].z; a4.w += awv*encr[i].w;
      }
      a4.x = red64(a4.x); a4.y = red64(a4.y); a4.z = red64(a4.z); a4.w = red64(a4.w);
      if (ts == 0) {
        s_ctmp[e4i*4+0] = a4.x; s_ctmp[e4i*4+1] = a4.y;
        s_ctmp[e4i*4+2] = a4.z; s_ctmp[e4i*4+3] = a4.w;
      }
      __syncthreads();
      if (tid < 8) {
        u32x4 w;
        w.x = pkh(s_ctmp[4*tid+0], s_ctmp[4*tid+1]);
        w.y = pkh(s_ctmp[4*tid+2], s_ctmp[4*tid+3]);
        w.z = tg; w.w = 0u;
        st_cg_u4(ct_rec + b_grp*128 + sub*8 + tid, w);
      }
    }
    // ===== P3a: LSTM0 x-part (fp16 dot2, independent of ctx) =====
    float acc[12];
    {
      #pragma unroll
      for (int r = 0; r < 12; ++r) acc[r] = 0.0f;
      const u32x4 xv = ((const u32x4*)x2h)[((size_t)t*NB + pb)*32 + kc];
      #pragma unroll
      for (int r = 0; r < 12; ++r) {
        const u32x4 w = ((const u32x4*)lw0x)[r*32 + kc];
        acc[r] = fdot2(xv.x, w.x, acc[r]); acc[r] = fdot2(xv.y, w.y, acc[r]);
        acc[r] = fdot2(xv.z, w.z, acc[r]); acc[r] = fdot2(xv.w, w.w, acc[r]);
      }
    }
    // ===== P3b: poll 4 ctx recs (batched retry) -> LSTM0 -> tagged h1 rec =====
    {
      u32x4 ra, rb, rc, rd;
      for (;;) {
        ld4u(ra, rb, rc, rd, ct_my + 2*kc, ct_my + 2*kc + 1,
             ct_my + 2*kc + 64, ct_my + 2*kc + 65);
        if (ra.z == tg && rb.z == tg && rc.z == tg && rd.z == tg) break;
        __builtin_amdgcn_s_sleep(1);
      }
      const u32x4 c0 = (u32x4){ra.x, ra.y, rb.x, rb.y};
      const u32x4 c1 = (u32x4){rc.x, rc.y, rd.x, rd.y};
      #pragma unroll
      for (int r = 0; r < 12; ++r) {
        const u32x4 w0 = ((const u32x4*)lw0c)[r*64 + kc];
        const u32x4 w1 = ((const u32x4*)lw0c)[r*64 + kc + 32];
        acc[r] = fdot2(c0.x, w0.x, acc[r]); acc[r] = fdot2(c0.y, w0.y, acc[r]);
        acc[r] = fdot2(c0.z, w0.z, acc[r]); acc[r] = fdot2(c0.w, w0.w, acc[r]);
        acc[r] = fdot2(c1.x, w1.x, acc[r]); acc[r] = fdot2(c1.y, w1.y, acc[r]);
        acc[r] = fdot2(c1.z, w1.z, acc[r]); acc[r] = fdot2(c1.w, w1.w, acc[r]);
      }
      #pragma unroll
      for (int r = 0; r < 12; ++r) acc[r] = red32(acc[r]);
      if (kc == 0) {
        float hv[4];
        #pragma unroll
        for (int h = 0; h < 4; ++h) {
          const float gi = acc[h]   + s_b0[h];
          const float gg = acc[4+h] + s_b0[4+h];
          const float go = acc[8+h] + s_b0[8+h];
          hv[h] = sigmf(go) * tanhf(sigmf(gi) * tanhf(gg));
        }
        u32x4 r;
        r.x = pkh(hv[0], hv[1]); r.y = pkh(hv[2], hv[3]);
        r.z = tg; r.w = 0u;
        st_cg_u4(h1_rec + pb*256 + bid, r);
      }
    }
    // ===== P4: poll h1 recs (2x batched 4) -> LSTM1 -> tagged h2 rec =====
    {
      #pragma unroll
      for (int r = 0; r < 12; ++r) acc[r] = 0.0f;
      u32x4 ra, rb, rc, rd;
      for (;;) {
        ld4u(ra, rb, rc, rd, h1_my + 2*kc, h1_my + 2*kc + 1,
             h1_my + 2*kc + 64, h1_my + 2*kc + 65);
        if (ra.z == tg && rb.z == tg && rc.z == tg && rd.z == tg) break;
        __builtin_amdgcn_s_sleep(1);
      }
      const u32x4 v0 = (u32x4){ra.x, ra.y, rb.x, rb.y};
      const u32x4 v1 = (u32x4){rc.x, rc.y, rd.x, rd.y};
      u32x4 re, rf, rg, rh;
      for (;;) {
        ld4u(re, rf, rg, rh, h1_my + 2*kc + 128, h1_my + 2*kc + 129,
             h1_my + 2*kc + 192, h1_my + 2*kc + 193);
        if (re.z == tg && rf.z == tg && rg.z == tg && rh.z == tg) break;
        __builtin_amdgcn_s_sleep(1);
      }
      const u32x4 v2 = (u32x4){re.x, re.y, rf.x, rf.y};
      const u32x4 v3 = (u32x4){rg.x, rg.y, rh.x, rh.y};
      #pragma unroll
      for (int r = 0; r < 12; ++r) {
        const u32x4* wp = (const u32x4*)lw1 + r*128 + kc;
        const u32x4 w0 = wp[0], w1 = wp[32], w2 = wp[64], w3 = wp[96];
        acc[r] = fdot2(v0.x, w0.x, acc[r]); acc[r] = fdot2(v0.y, w0.y, acc[r]);
        acc[r] = fdot2(v0.z, w0.z, acc[r]); acc[r] = fdot2(v0.w, w0.w, acc[r]);
        acc[r] = fdot2(v1.x, w1.x, acc[r]); acc[r] = fdot2(v1.y, w1.y, acc[r]);
        acc[r] = fdot2(v1.z, w1.z, acc[r]); acc[r] = fdot2(v1.w, w1.w, acc[r]);
        acc[r] = fdot2(v2.x, w2.x, acc[r]); acc[r] = fdot2(v2.y, w2.y, acc[r]);
        acc[r] = fdot2(v2.z, w2.z, acc[r]); acc[r] = fdot2(v2.w, w2.w, acc[r]);
        acc[r] = fdot2(v3.x, w3.x, acc[r]); acc[r] = fdot2(v3.y, w3.y, acc[r]);
        acc[r] = fdot2(v3.z, w3.z, acc[r]); acc[r] = fdot2(v3.w, w3.w, acc[r]);
      }
      #pragma unroll
      for (int r = 0; r < 12; ++r) acc[r] = red32(acc[r]);
      if (kc == 0) {
        float hv[4];
        #pragma unroll
        for (int h = 0; h < 4; ++h) {
          const float gi = acc[h]   + s_b1[h];
          const float gg = acc[4+h] + s_b1[4+h];
          const float go = acc[8+h] + s_b1[8+h];
          hv[h] = sigmf(go) * tanhf(sigmf(gi) * tanhf(gg));
        }
        f4 r;
        r.x = __uint_as_float(pkh(hv[0], hv[1]));
        r.y = __uint_as_float(pkh(hv[2], hv[3]));
        r.z = __uint_as_float(tg); r.w = 0.f;
        st_cg_f4(h2_rec + pb*256 + bid, r);
      }
    }
    // ===== P5: poll h2 recs + ctx recs -> s_dec ; q -> qv recs =====
    {
      if (tid < 256) {
        const f4* hp = h2_rec + b_grp*256 + tid;
        f4 v;
        do { v = ld_cg_f4(hp); } while (__float_as_uint(v.z) != tg);
        const unsigned u0 = __float_as_uint(v.x), u1 = __float_as_uint(v.y);
        s_dec[4*tid+0] = hlo(u0); s_dec[4*tid+1] = hhi(u0);
        s_dec[4*tid+2] = hlo(u1); s_dec[4*tid+3] = hhi(u1);
      } else if (tid < 384) {
        const int i = tid - 256;
        const u32x4* cp = ct_rec + b_grp*128 + i;
        u32x4 v;
        do { v = ld_cg_u4(cp); } while (v.z != tg);
        s_dec[HH + 4*i + 0] = hlo(v.x); s_dec[HH + 4*i + 1] = hhi(v.x);
        s_dec[HH + 4*i + 2] = hlo(v.y); s_dec[HH + 4*i + 3] = hhi(v.y);
      }
      __syncthreads();
      const int row = tid >> 6;
      const int kq  = tid & 63;
      const int a   = sub*8 + row;
      const f4* w4 = (const f4*)(lstm_proj_w + (size_t)a*HH);
      const f4* s4 = (const f4*)s_dec;
      float a2 = 0.0f;
      #pragma unroll
      for (int i = 0; i < 4; ++i) a2 += dot4(s4[kq + 64*i], w4[kq + 64*i]);
      a2 = red64(a2);
      if (kq == 0) s_qtmp[row] = a2;
      __syncthreads();
      if (tid < 2) {
        f4 r;
        r.x = __uint_as_float(pkh(s_qtmp[4*tid+0], s_qtmp[4*tid+1]));
        r.y = __uint_as_float(pkh(s_qtmp[4*tid+2], s_qtmp[4*tid+3]));
        r.z = __uint_as_float(tg); r.w = 0.f;
        st_cg_f4(qv_rec + (b_grp*16 + sub)*2 + tid, r);
      }
    }
  }
  // ===== epilogue: mel/stop for t = TD-1 (s_dec holds h2|ctx of last step) =====
  __syncthreads();
  {
    const int ol = tid >> 5, kq = tid & 31;
    if (ol < 6) {
      const int m = sub*6 + ol;
      if (m < 81) {
        const float* wrow = (m < NMEL) ? (proj_w + (size_t)m*(HH+EE)) : stop_w;
        const f4* w4 = (const f4*)wrow;
        const f4* s4 = (const f4*)s_dec;
        float a2 = 0.0f;
        #pragma unroll
        for (int i = 0; i < 12; ++i) a2 += dot4(s4[kq + 32*i], w4[kq + 32*i]);
        a2 = red32(a2);
        if (kq == 0) {
          if (m < NMEL) out[(b_grp*TD + (TD-1))*NMEL + m] = a2 + proj_b[m];
          else          out[NB*TD*NMEL + b_grp*TD + (TD-1)] = a2 + stop_b[0];
        }
      }
    }
  }
}

extern "C" void kernel_launch(void* const* d_in, const int* in_sizes, int n_in,
                              void* d_out, int out_size, void* d_ws, size_t ws_size,
                              hipStream_t stream) {
  (void)in_sizes; (void)n_in; (void)out_size; (void)ws_size;
  const float* enc         = (const float*)d_in[0];
  const float* mels        = (const float*)d_in[1];
  const float* enc_proj_w  = (const float*)d_in[2];
  const float* lstm_proj_w = (const float*)d_in[3];
  const float* loc_conv_w  = (const float*)d_in[4];
  const float* loc_conv_b  = (const float*)d_in[5];
  const float* loc_dense_w = (const float*)d_in[6];
  const float* loc_dense_b = (const float*)d_in[7];
  const float* e_w         = (const float*)d_in[8];
  const float* e_b         = (const float*)d_in[9];
  const float* prenet1_w   = (const float*)d_in[10];
  const float* prenet2_w   = (const float*)d_in[11];
  const float* w_ih0       = (const float*)d_in[12];
  const float* b_ih0       = (const float*)d_in[14];
  const float* b_hh0       = (const float*)d_in[15];
  const float* w_ih1       = (const float*)d_in[16];
  const float* b_ih1       = (const float*)d_in[18];
  const float* b_hh1       = (const float*)d_in[19];
  const float* proj_w      = (const float*)d_in[20];
  const float* proj_b      = (const float*)d_in[21];
  const float* stop_w      = (const float*)d_in[22];
  const float* stop_b      = (const float*)d_in[23];
  const int*   text_len    = (const int*)d_in[24];
  float* ws  = (float*)d_ws;
  float* out = (float*)d_out;

  static int attr_set = 0;
  if (!attr_set) {
    hipFuncSetAttribute((const void*)k_main,
                        hipFuncAttributeMaxDynamicSharedMemorySize, DYN_BYTES);
    attr_set = 1;
  }

  k_init<<<dim3(32), dim3(256), 0, stream>>>(ws);
  k_prenet<<<dim3(TD*NB), dim3(256), 0, stream>>>(mels, prenet1_w, prenet2_w, ws);
  k_procenc<<<dim3(NB*TE), dim3(128), 0, stream>>>(enc, enc_proj_w, ws + OFF_PE);

  k_main<<<dim3(256), dim3(512), DYN_BYTES, stream>>>(
      enc, lstm_proj_w, loc_conv_w, loc_conv_b, loc_dense_w, loc_dense_b,
      e_w, e_b, w_ih0, b_ih0, b_hh0, w_ih1, b_ih1, b_hh1,
      proj_w, proj_b, stop_w, stop_b, text_len, ws, out);
}

// Round 13
// 3718.562 us; speedup vs baseline: 1.4553x; 1.4553x over previous
//
#include <hip/hip_runtime.h>
#include <math.h>

#define NB   16
#define TE   256
#define TD   200
#define EE   512
#define ATT  128
#define PREN 256
#define HH   1024
#define NMEL 80
#define NLOC 32
#define KWW  31
#define PADW 15

// workspace offsets (float slots)
#define OFF_X2H  0                          // [TD][NB][128] u32 (256 fp16)
#define OFF_PE   (OFF_X2H + TD*NB*128)      // [NB][TE][ATT] f32
#define OFF_ENR  (OFF_PE + NB*TE*ATT)       // [NB][16][6] f4 recs {3 f32, tag}
#define OFF_CTR  (OFF_ENR + NB*16*6*4)      // [NB][128] u32x4 recs {2 u32, tag, 0}
#define OFF_H1H  (OFF_CTR + NB*128*4)       // [NB][512] u32 (untagged, gbar)
#define OFF_H2R  (OFF_H1H + NB*512)         // [NB][256] f4 recs {h01,h23,tag,0}
#define OFF_QVR  (OFF_H2R + NB*256*4)       // [NB][16][2] f4 recs
#define OFF_BAR  (OFF_QVR + NB*16*2*4)      // flags (ARR_G only)
#define BAR_U32  4096
#define ARR_G 0

// dynamic LDS (u32 counts): fp16-packed weight slices
#define LW0X_U32 (12*128)
#define LW0C_U32 (12*256)
#define LW1_U32  (12*512)
#define DYN_BYTES ((LW0X_U32 + LW0C_U32 + LW1_U32)*4)

typedef float f4 __attribute__((ext_vector_type(4)));
typedef unsigned int u32x4 __attribute__((ext_vector_type(4)));
typedef unsigned int u32x2 __attribute__((ext_vector_type(2)));
typedef _Float16 h2t __attribute__((ext_vector_type(2)));

__device__ __forceinline__ float fast_sigm(float x) { return 1.0f / (1.0f + __expf(-x)); }
__device__ __forceinline__ float fast_tanh(float x) { return 1.0f - 2.0f / (__expf(2.0f*x) + 1.0f); }
__device__ __forceinline__ float dot4(f4 a, f4 b) {
  return a.x*b.x + a.y*b.y + a.z*b.z + a.w*b.w;
}
__device__ __forceinline__ float red32(float v) {
  v += __shfl_down(v, 16, 32); v += __shfl_down(v, 8, 32);
  v += __shfl_down(v, 4, 32);  v += __shfl_down(v, 2, 32);
  v += __shfl_down(v, 1, 32);
  return v;
}
__device__ __forceinline__ float red64(float v) {
  v += __shfl_down(v, 32); v += __shfl_down(v, 16); v += __shfl_down(v, 8);
  v += __shfl_down(v, 4);  v += __shfl_down(v, 2);  v += __shfl_down(v, 1);
  return v;
}
__device__ __forceinline__ float fdot2(unsigned a, unsigned b, float c) {
  return __builtin_amdgcn_fdot2(__builtin_bit_cast(h2t, a),
                                __builtin_bit_cast(h2t, b), c, false);
}
__device__ __forceinline__ unsigned pkh(float a, float b) {
  h2t h; h.x = (_Float16)a; h.y = (_Float16)b;
  return __builtin_bit_cast(unsigned, h);
}
__device__ __forceinline__ float hlo(unsigned u) {
  return (float)__builtin_bit_cast(h2t, u).x;
}
__device__ __forceinline__ float hhi(unsigned u) {
  return (float)__builtin_bit_cast(h2t, u).y;
}

// ---- LLC-coherent (L1+L2 bypass) accessors ----
__device__ __forceinline__ unsigned ld_cg_u32(const unsigned* p) {
  unsigned r;
  asm volatile("global_load_dword %0, %1, off sc0 sc1\n\ts_waitcnt vmcnt(0)"
               : "=v"(r) : "v"(p) : "memory");
  return r;
}
__device__ __forceinline__ void st_cg_u32(unsigned* p, unsigned v) {
  asm volatile("global_store_dword %0, %1, off sc0 sc1" :: "v"(p), "v"(v) : "memory");
}
__device__ __forceinline__ f4 ld_cg_f4(const f4* p) {
  f4 r;
  asm volatile("global_load_dwordx4 %0, %1, off sc0 sc1\n\ts_waitcnt vmcnt(0)"
               : "=v"(r) : "v"(p) : "memory");
  return r;
}
__device__ __forceinline__ void st_cg_f4(f4* p, f4 v) {
  asm volatile("global_store_dwordx4 %0, %1, off sc0 sc1" :: "v"(p), "v"(v) : "memory");
}
__device__ __forceinline__ u32x4 ld_cg_u4(const void* p) {
  u32x4 r;
  asm volatile("global_load_dwordx4 %0, %1, off sc0 sc1\n\ts_waitcnt vmcnt(0)"
               : "=v"(r) : "v"(p) : "memory");
  return r;
}
__device__ __forceinline__ void st_cg_u4(void* p, u32x4 v) {
  asm volatile("global_store_dwordx4 %0, %1, off sc0 sc1" :: "v"(p), "v"(v) : "memory");
}
__device__ __forceinline__ void st_cg_u2(void* p, u32x2 v) {
  asm volatile("global_store_dwordx2 %0, %1, off sc0 sc1" :: "v"(p), "v"(v) : "memory");
}
// ---- L2-scope (sc0 only) accessors: fast path for same-XCD exchanges ----
__device__ __forceinline__ f4 ld_l2_f4(const f4* p) {
  f4 r;
  asm volatile("global_load_dwordx4 %0, %1, off sc0\n\ts_waitcnt vmcnt(0)"
               : "=v"(r) : "v"(p) : "memory");
  return r;
}
__device__ __forceinline__ void st_l2_f4(f4* p, f4 v) {
  asm volatile("global_store_dwordx4 %0, %1, off sc0" :: "v"(p), "v"(v) : "memory");
}
__device__ __forceinline__ u32x4 ld_l2_u4(const void* p) {
  u32x4 r;
  asm volatile("global_load_dwordx4 %0, %1, off sc0\n\ts_waitcnt vmcnt(0)"
               : "=v"(r) : "v"(p) : "memory");
  return r;
}
__device__ __forceinline__ void st_l2_u4(void* p, u32x4 v) {
  asm volatile("global_store_dwordx4 %0, %1, off sc0" :: "v"(p), "v"(v) : "memory");
}
__device__ __forceinline__ void ld4u(u32x4& a, u32x4& b, u32x4& c, u32x4& d,
                                     const void* pa, const void* pb,
                                     const void* pc, const void* pd) {
  asm volatile(
    "global_load_dwordx4 %0, %4, off sc0 sc1\n\t"
    "global_load_dwordx4 %1, %5, off sc0 sc1\n\t"
    "global_load_dwordx4 %2, %6, off sc0 sc1\n\t"
    "global_load_dwordx4 %3, %7, off sc0 sc1\n\t"
    "s_waitcnt vmcnt(0)"
    : "=&v"(a), "=&v"(b), "=&v"(c), "=&v"(d)
    : "v"(pa), "v"(pb), "v"(pc), "v"(pd) : "memory");
}

// ---- single global barrier (h1 all-to-all), round-6 proven ----
__device__ __forceinline__ void g_arrive(unsigned* bar, unsigned e) {
  __syncthreads();
  if (threadIdx.x == 0) st_cg_u32(bar + ARR_G + blockIdx.x * 16, e);
}
__device__ __forceinline__ void g_wait(unsigned* bar, unsigned e) {
  if (threadIdx.x < 256) {
    while (ld_cg_u32(bar + ARR_G + threadIdx.x * 16) < e) {}
  }
  __syncthreads();
}

// ---------------- init: zero ALL tagged record regions + flags ----------------
__global__ void k_init(float* __restrict__ ws) {
  const int gid = blockIdx.x * 256 + threadIdx.x;
  f4* enr = (f4*)(ws + OFF_ENR);
  u32x4* ctr = (u32x4*)(ws + OFF_CTR);
  f4* h2r = (f4*)(ws + OFF_H2R);
  f4* qvr = (f4*)(ws + OFF_QVR);
  unsigned* bar = (unsigned*)(ws + OFF_BAR);
  const f4 z = (f4){0.f, 0.f, 0.f, 0.f};
  const u32x4 zu = (u32x4){0u, 0u, 0u, 0u};
  for (int i = gid; i < NB*16*6; i += 32*256) st_cg_f4(enr + i, z);
  for (int i = gid; i < NB*128; i += 32*256) st_cg_u4(ctr + i, zu);
  for (int i = gid; i < NB*256; i += 32*256) st_cg_f4(h2r + i, z);
  for (int i = gid; i < NB*32; i += 32*256) st_cg_f4(qvr + i, z);
  for (int i = gid; i < BAR_U32; i += 32*256) st_cg_u32(bar + i, 0u);
}

// ---------------- prenet (fp16 output) ----------------
__global__ void k_prenet(const float* __restrict__ mels,
                         const float* __restrict__ w1,
                         const float* __restrict__ w2,
                         float* __restrict__ ws) {
  const int t = blockIdx.x >> 4;
  const int b = blockIdx.x & 15;
  const int j = threadIdx.x;
  __shared__ float s_in[NMEL];
  __shared__ float s_x1[PREN];
  if (j < NMEL) s_in[j] = (t == 0) ? 0.0f : mels[(b*TD + (t-1))*NMEL + j];
  __syncthreads();
  float a1 = 0.0f;
  #pragma unroll 8
  for (int k = 0; k < NMEL; ++k) a1 += s_in[k] * w1[j*NMEL + k];
  s_x1[j] = fmaxf(a1, 0.0f);
  __syncthreads();
  float a2 = 0.0f;
  #pragma unroll 8
  for (int k = 0; k < PREN; ++k) a2 += s_x1[k] * w2[j*PREN + k];
  ((_Float16*)(ws + OFF_X2H))[((size_t)t*NB + b)*256 + j] = (_Float16)fmaxf(a2, 0.0f);
}

// ---------------- processed encoder ----------------
__global__ void k_procenc(const float* __restrict__ enc,
                          const float* __restrict__ w,
                          float* __restrict__ pe) {
  const int bt = blockIdx.x;
  const int a = threadIdx.x;
  __shared__ float s_e[EE];
  for (int k = a; k < EE; k += 128) s_e[k] = enc[bt*EE + k];
  __syncthreads();
  float acc = 0.0f;
  #pragma unroll 8
  for (int k = 0; k < EE; ++k) acc += s_e[k] * w[a*EE + k];
  pe[bt*ATT + a] = acc;
}

// ---------------- main decoder loop (dataflow + 1 gbar/step) ----------------
__global__ void __launch_bounds__(512, 1) k_main(
    const float* __restrict__ enc,
    const float* __restrict__ lstm_proj_w,
    const float* __restrict__ loc_conv_w,
    const float* __restrict__ loc_conv_b,
    const float* __restrict__ loc_dense_w,
    const float* __restrict__ loc_dense_b,
    const float* __restrict__ e_w,
    const float* __restrict__ e_b,
    const float* __restrict__ w_ih0,
    const float* __restrict__ b_ih0,
    const float* __restrict__ b_hh0,
    const float* __restrict__ w_ih1,
    const float* __restrict__ b_ih1,
    const float* __restrict__ b_hh1,
    const float* __restrict__ proj_w,
    const float* __restrict__ proj_b,
    const float* __restrict__ stop_w,
    const float* __restrict__ stop_b,
    const int*   __restrict__ text_len,
    float* __restrict__ ws,
    float* __restrict__ out) {
  const int bid = blockIdx.x;
  const int tid = threadIdx.x;

  const unsigned* x2h = (const unsigned*)(ws + OFF_X2H);
  float* pe  = ws + OFF_PE;
  f4* en_rec = (f4*)(ws + OFF_ENR);
  u32x4* ct_rec = (u32x4*)(ws + OFF_CTR);
  unsigned* h1h = (unsigned*)(ws + OFF_H1H);
  f4* h2_rec = (f4*)(ws + OFF_H2R);
  f4* qv_rec = (f4*)(ws + OFF_QVR);
  unsigned* bar = (unsigned*)(ws + OFF_BAR);

  __shared__ __align__(16) float s_ldw[NLOC*ATT];   // loc_dense_w^T [c][a] f32
  __shared__ float s_awcf[TE];                      // local cumulative attn
  __shared__ float s_loc[16*33];
  __shared__ float s_red[16];
  __shared__ float s_en[256];
  __shared__ float s_aw[256];
  __shared__ float s_entmp[16];
  __shared__ float s_qtmp[8];
  __shared__ float s_ctmp[32];
  __shared__ __align__(16) float s_q[ATT];
  __shared__ __align__(16) float s_dec[HH+EE];      // [h2 f32 | ctx f32]
  __shared__ float s_b0[12], s_b1[12];
  extern __shared__ __align__(16) unsigned dynlds_u[];
  unsigned* lw0x = dynlds_u;                 // [12][128] u32
  unsigned* lw0c = lw0x + LW0X_U32;          // [12][256] u32
  unsigned* lw1  = lw0c + LW0C_U32;          // [12][512] u32

  const int b_grp = bid & 15;
  const int sub   = bid >> 4;
  const int h0    = bid * 4;

  // ---- one-time staging ----
  for (int i = tid; i < NLOC*ATT; i += 512) {
    int c = i >> 7, a = i & 127;
    s_ldw[i] = loc_dense_w[a*NLOC + c];
  }
  if (tid < 12) {
    int g = tid >> 2, h = tid & 3;
    int gr = (g == 0 ? 0 : (g == 1 ? 2048 : 3072)) + h0 + h;
    s_b0[tid] = b_ih0[gr] + b_hh0[gr];
    s_b1[tid] = b_ih1[gr] + b_hh1[gr];
  }
  for (int i = tid; i < LW0X_U32; i += 512) {
    int r = i >> 7, c = i & 127;
    int g = r >> 2, h = r & 3;
    int grow = (g == 0 ? 0 : (g == 1 ? 2048 : 3072)) + h0 + h;
    const float* wr = w_ih0 + (size_t)grow*768;
    lw0x[i] = pkh(wr[2*c], wr[2*c+1]);
  }
  for (int i = tid; i < LW0C_U32; i += 512) {
    int r = i >> 8, c = i & 255;
    int g = r >> 2, h = r & 3;
    int grow = (g == 0 ? 0 : (g == 1 ? 2048 : 3072)) + h0 + h;
    const float* wr = w_ih0 + (size_t)grow*768 + 256;
    lw0c[i] = pkh(wr[2*c], wr[2*c+1]);
  }
  for (int i = tid; i < LW1_U32; i += 512) {
    int r = i >> 9, c = i & 511;
    int g = r >> 2, h = r & 3;
    int grow = (g == 0 ? 0 : (g == 1 ? 2048 : 3072)) + h0 + h;
    const float* wr = w_ih1 + (size_t)grow*1024;
    lw1[i] = pkh(wr[2*c], wr[2*c+1]);
  }
  if (tid < 256) s_awcf[tid] = 0.0f;

  const int   lenb = text_len[b_grp];
  const float eb0  = e_b[0];
  // P1 invariants
  const int tl = tid >> 5;
  const int j  = tid & 31;
  float lcw_r[KWW];
  #pragma unroll
  for (int k = 0; k < KWW; ++k) lcw_r[k] = loc_conv_w[j*KWW + k];
  const float lcb_r = loc_conv_b[j];
  const f4 db_r = *(const f4*)(loc_dense_b + 4*j);
  const f4 ew_r = *(const f4*)(e_w + 4*j);
  const f4 pe_r = *(const f4*)(pe + (size_t)(b_grp*TE + sub*16 + tl)*ATT + 4*j);
  const f4 ps_r = pe_r + db_r;
  // P2 invariants
  const int e4i = tid >> 6;
  const int ts  = tid & 63;
  f4 encr[4];
  {
    const f4* enc4 = (const f4*)(enc + (size_t)b_grp*TE*EE);
    #pragma unroll
    for (int i = 0; i < 4; ++i)
      encr[i] = enc4[(size_t)(ts + 64*i)*(EE/4) + sub*8 + e4i];
  }
  // en-poll invariants (tid<96): si = tid/6, rr = tid%6
  const int en_si = tid / 6;
  const int en_rr = tid - en_si*6;
  const f4* en_myrec = en_rec + (b_grp*16 + en_si)*6 + en_rr;
  // P3/P4 mapping
  const int pb = tid >> 5;
  const int kc = tid & 31;
  const u32x4* ct_my = ct_rec + pb*128;      // this thread's ctx recs base
  __syncthreads();

  unsigned eg = 0;

  for (int t = 0; t < TD; ++t) {
    const unsigned tg = (unsigned)(t + 1);
    // ===== P1a: conv from s_awcf + loc_dense pre-term (all-LDS) =====
    f4 pre;
    {
      float cv = lcb_r;
      const int pos = sub*16 + tl;
      #pragma unroll
      for (int k = 0; k < KWW; ++k) {
        const int g = pos - PADW + k;
        const float av = (g >= 0 && g < TE) ? s_awcf[g] : 0.0f;
        cv += av * lcw_r[k];
      }
      s_loc[tl*33 + j] = cv;
      __syncthreads();
      f4 d4 = (f4){0.f, 0.f, 0.f, 0.f};
      #pragma unroll 8
      for (int c = 0; c < NLOC; ++c) {
        const float lv = s_loc[tl*33 + c];
        const f4 w4 = ((const f4*)s_ldw)[c*32 + j];
        d4.x += lv*w4.x; d4.y += lv*w4.y; d4.z += lv*w4.z; d4.w += lv*w4.w;
      }
      pre = ps_r + d4;
    }
    // ===== P1b: hybrid poll qv recs (tag==t), energies -> tagged en recs =====
    {
      if (tid < 32) {
        const int src = tid >> 1, r = tid & 1;
        const f4* qp = qv_rec + (b_grp*16 + src)*2 + r;
        f4 v = ld_l2_f4(qp);                               // L2 fast path
        while (__float_as_uint(v.z) != (unsigned)t) v = ld_cg_f4(qp);
        const unsigned u0 = __float_as_uint(v.x), u1 = __float_as_uint(v.y);
        const int base = src*8 + r*4;
        s_q[base+0] = hlo(u0); s_q[base+1] = hhi(u0);
        s_q[base+2] = hlo(u1); s_q[base+3] = hhi(u1);
      }
      __syncthreads();
      const f4 q4 = *(const f4*)(s_q + 4*j);
      float acc = fast_tanh(pre.x+q4.x)*ew_r.x + fast_tanh(pre.y+q4.y)*ew_r.y
                + fast_tanh(pre.z+q4.z)*ew_r.z + fast_tanh(pre.w+q4.w)*ew_r.w;
      acc = red32(acc);
      if (j == 0) {
        float evv = acc + eb0;
        const int tt = sub*16 + tl;
        if (tt >= lenb) evv = -1e9f;
        s_entmp[tl] = evv;
      }
      __syncthreads();
      if (tid < 6) {
        f4 r = (f4){0.f, 0.f, 0.f, __uint_as_float(tg)};
        const int base = 3*tid;
        r.x = s_entmp[base];
        if (base + 1 < 16) r.y = s_entmp[base+1];
        if (base + 2 < 16) r.z = s_entmp[base+2];
        f4* dst = en_rec + (b_grp*16 + sub)*6 + tid;
        st_l2_f4(dst, r);                                  // local L2
        st_cg_f4(dst, r);                                  // LLC (global safety)
      }
    }
    // ===== P2: {en hybrid poll (tid<96)} || {mel shadow (tid 128..319)} =====
    {
      if (tid < 96) {
        f4 v = ld_l2_f4(en_myrec);                         // L2 fast path
        while (__float_as_uint(v.w) != tg) v = ld_cg_f4(en_myrec);
        const int base = en_si*16 + 3*en_rr;
        s_en[base] = v.x;
        if (3*en_rr + 1 < 16) s_en[base+1] = v.y;
        if (3*en_rr + 2 < 16) s_en[base+2] = v.z;
      } else if (t > 0 && tid >= 128 && tid < 320) {
        const int ol = (tid - 128) >> 5, kq = tid & 31;
        const int m = sub*6 + ol;
        if (m < 81) {
          const float* wrow = (m < NMEL) ? (proj_w + (size_t)m*(HH+EE)) : stop_w;
          const f4* w4 = (const f4*)wrow;
          const f4* s4 = (const f4*)s_dec;
          float a2 = 0.0f;
          #pragma unroll
          for (int i = 0; i < 12; ++i) a2 += dot4(s4[kq + 32*i], w4[kq + 32*i]);
          a2 = red32(a2);
          if (kq == 0) {
            if (m < NMEL) out[(b_grp*TD + (t-1))*NMEL + m] = a2 + proj_b[m];
            else          out[NB*TD*NMEL + b_grp*TD + (t-1)] = a2 + stop_b[0];
          }
        }
      }
      __syncthreads();
      // softmax (no max-sub: |en| <= ~2 bounded; masked -1e9 -> exp -> 0)
      float p = 0.f;
      if (tid < 256) {
        p = __expf(s_en[tid]);
        float sm = p;
        #pragma unroll
        for (int d = 32; d > 0; d >>= 1) sm += __shfl_xor(sm, d);
        if ((tid & 63) == 0) s_red[8 + (tid >> 6)] = sm;
      }
      __syncthreads();
      const float inv = 1.0f / (s_red[8] + s_red[9] + s_red[10] + s_red[11]);
      if (tid < 256) {
        const float aw = p * inv;
        s_aw[tid] = aw;
        s_awcf[tid] += aw;
      }
      __syncthreads();
      f4 a4 = (f4){0.f, 0.f, 0.f, 0.f};
      #pragma unroll
      for (int i = 0; i < 4; ++i) {
        const float awv = s_aw[ts + 64*i];
        a4.x += awv*encr[i].x; a4.y += awv*encr[i].y;
        a4.z += awv*encr[i].z; a4.w += awv*encr[i].w;
      }
      a4.x = red64(a4.x); a4.y = red64(a4.y); a4.z = red64(a4.z); a4.w = red64(a4.w);
      if (ts == 0) {
        s_ctmp[e4i*4+0] = a4.x; s_ctmp[e4i*4+1] = a4.y;
        s_ctmp[e4i*4+2] = a4.z; s_ctmp[e4i*4+3] = a4.w;
      }
      __syncthreads();
      if (tid < 8) {
        u32x4 w;
        w.x = pkh(s_ctmp[4*tid+0], s_ctmp[4*tid+1]);
        w.y = pkh(s_ctmp[4*tid+2], s_ctmp[4*tid+3]);
        w.z = tg; w.w = 0u;
        u32x4* dst = ct_rec + b_grp*128 + sub*8 + tid;
        st_l2_u4(dst, w);                                  // local L2 (P5 path)
        st_cg_u4(dst, w);                                  // LLC (P3b cross-XCD)
      }
    }
    // ===== P3a: LSTM0 x-part (fp16 dot2, independent of ctx) =====
    float acc[12];
    {
      #pragma unroll
      for (int r = 0; r < 12; ++r) acc[r] = 0.0f;
      const u32x4 xv = ((const u32x4*)x2h)[((size_t)t*NB + pb)*32 + kc];
      #pragma unroll
      for (int r = 0; r < 12; ++r) {
        const u32x4 w = ((const u32x4*)lw0x)[r*32 + kc];
        acc[r] = fdot2(xv.x, w.x, acc[r]); acc[r] = fdot2(xv.y, w.y, acc[r]);
        acc[r] = fdot2(xv.z, w.z, acc[r]); acc[r] = fdot2(xv.w, w.w, acc[r]);
      }
    }
    // ===== P3b: poll 4 ctx recs (batched retry, cross-XCD) -> LSTM0 -> h1 =====
    {
      u32x4 ra, rb, rc, rd;
      for (;;) {
        ld4u(ra, rb, rc, rd, ct_my + 2*kc, ct_my + 2*kc + 1,
             ct_my + 2*kc + 64, ct_my + 2*kc + 65);
        if (ra.z == tg && rb.z == tg && rc.z == tg && rd.z == tg) break;
        __builtin_amdgcn_s_sleep(1);
      }
      const u32x4 c0 = (u32x4){ra.x, ra.y, rb.x, rb.y};
      const u32x4 c1 = (u32x4){rc.x, rc.y, rd.x, rd.y};
      #pragma unroll
      for (int r = 0; r < 12; ++r) {
        const u32x4 w0 = ((const u32x4*)lw0c)[r*64 + kc];
        const u32x4 w1 = ((const u32x4*)lw0c)[r*64 + kc + 32];
        acc[r] = fdot2(c0.x, w0.x, acc[r]); acc[r] = fdot2(c0.y, w0.y, acc[r]);
        acc[r] = fdot2(c0.z, w0.z, acc[r]); acc[r] = fdot2(c0.w, w0.w, acc[r]);
        acc[r] = fdot2(c1.x, w1.x, acc[r]); acc[r] = fdot2(c1.y, w1.y, acc[r]);
        acc[r] = fdot2(c1.z, w1.z, acc[r]); acc[r] = fdot2(c1.w, w1.w, acc[r]);
      }
      #pragma unroll
      for (int r = 0; r < 12; ++r) acc[r] = red32(acc[r]);
      if (kc == 0) {
        float hv[4];
        #pragma unroll
        for (int h = 0; h < 4; ++h) {
          const float gi = acc[h]   + s_b0[h];
          const float gg = acc[4+h] + s_b0[4+h];
          const float go = acc[8+h] + s_b0[8+h];
          hv[h] = fast_sigm(go) * fast_tanh(fast_sigm(gi) * fast_tanh(gg));
        }
        u32x2 stv; stv.x = pkh(hv[0], hv[1]); stv.y = pkh(hv[2], hv[3]);
        st_cg_u2((u32x2*)h1h + pb*256 + bid, stv);
      }
    }
    g_arrive(bar, ++eg);
    g_wait(bar, eg);                  // h1 all-to-all ready
    // ===== P4: LSTM1 (fp16 dot2) -> h2 tagged rec =====
    {
      #pragma unroll
      for (int r = 0; r < 12; ++r) acc[r] = 0.0f;
      u32x4 v0, v1, v2, v3;
      const u32x4* hp = (const u32x4*)h1h + pb*128 + kc;
      ld4u(v0, v1, v2, v3, hp, hp+32, hp+64, hp+96);
      #pragma unroll
      for (int r = 0; r < 12; ++r) {
        const u32x4* wp = (const u32x4*)lw1 + r*128 + kc;
        const u32x4 w0 = wp[0], w1 = wp[32], w2 = wp[64], w3 = wp[96];
        acc[r] = fdot2(v0.x, w0.x, acc[r]); acc[r] = fdot2(v0.y, w0.y, acc[r]);
        acc[r] = fdot2(v0.z, w0.z, acc[r]); acc[r] = fdot2(v0.w, w0.w, acc[r]);
        acc[r] = fdot2(v1.x, w1.x, acc[r]); acc[r] = fdot2(v1.y, w1.y, acc[r]);
        acc[r] = fdot2(v1.z, w1.z, acc[r]); acc[r] = fdot2(v1.w, w1.w, acc[r]);
        acc[r] = fdot2(v2.x, w2.x, acc[r]); acc[r] = fdot2(v2.y, w2.y, acc[r]);
        acc[r] = fdot2(v2.z, w2.z, acc[r]); acc[r] = fdot2(v2.w, w2.w, acc[r]);
        acc[r] = fdot2(v3.x, w3.x, acc[r]); acc[r] = fdot2(v3.y, w3.y, acc[r]);
        acc[r] = fdot2(v3.z, w3.z, acc[r]); acc[r] = fdot2(v3.w, w3.w, acc[r]);
      }
      #pragma unroll
      for (int r = 0; r < 12; ++r) acc[r] = red32(acc[r]);
      if (kc == 0) {
        float hv[4];
        #pragma unroll
        for (int h = 0; h < 4; ++h) {
          const float gi = acc[h]   + s_b1[h];
          const float gg = acc[4+h] + s_b1[4+h];
          const float go = acc[8+h] + s_b1[8+h];
          hv[h] = fast_sigm(go) * fast_tanh(fast_sigm(gi) * fast_tanh(gg));
        }
        f4 r;
        r.x = __uint_as_float(pkh(hv[0], hv[1]));
        r.y = __uint_as_float(pkh(hv[2], hv[3]));
        r.z = __uint_as_float(tg); r.w = 0.f;
        st_cg_f4(h2_rec + pb*256 + bid, r);
      }
    }
    // ===== P5: poll h2 recs (LLC) + ctx recs (hybrid) -> s_dec ; q -> qv =====
    {
      if (tid < 256) {
        const f4* hp = h2_rec + b_grp*256 + tid;
        f4 v;
        do { v = ld_cg_f4(hp); } while (__float_as_uint(v.z) != tg);
        const unsigned u0 = __float_as_uint(v.x), u1 = __float_as_uint(v.y);
        s_dec[4*tid+0] = hlo(u0); s_dec[4*tid+1] = hhi(u0);
        s_dec[4*tid+2] = hlo(u1); s_dec[4*tid+3] = hhi(u1);
      } else if (tid < 384) {
        const int i = tid - 256;
        const u32x4* cp = ct_rec + b_grp*128 + i;
        u32x4 v = ld_l2_u4(cp);                            // L2 fast path
        while (v.z != tg) v = ld_cg_u4(cp);
        s_dec[HH + 4*i + 0] = hlo(v.x); s_dec[HH + 4*i + 1] = hhi(v.x);
        s_dec[HH + 4*i + 2] = hlo(v.y); s_dec[HH + 4*i + 3] = hhi(v.y);
      }
      __syncthreads();
      const int row = tid >> 6;
      const int kq  = tid & 63;
      const int a   = sub*8 + row;
      const f4* w4 = (const f4*)(lstm_proj_w + (size_t)a*HH);
      const f4* s4 = (const f4*)s_dec;
      float a2 = 0.0f;
      #pragma unroll
      for (int i = 0; i < 4; ++i) a2 += dot4(s4[kq + 64*i], w4[kq + 64*i]);
      a2 = red64(a2);
      if (kq == 0) s_qtmp[row] = a2;
      __syncthreads();
      if (tid < 2) {
        f4 r;
        r.x = __uint_as_float(pkh(s_qtmp[4*tid+0], s_qtmp[4*tid+1]));
        r.y = __uint_as_float(pkh(s_qtmp[4*tid+2], s_qtmp[4*tid+3]));
        r.z = __uint_as_float(tg); r.w = 0.f;
        f4* dst = qv_rec + (b_grp*16 + sub)*2 + tid;
        st_l2_f4(dst, r);                                  // local L2
        st_cg_f4(dst, r);                                  // LLC (safety)
      }
    }
  }
  // ===== epilogue: mel/stop for t = TD-1 (s_dec holds h2|ctx of last step) =====
  __syncthreads();
  {
    const int ol = tid >> 5, kq = tid & 31;
    if (ol < 6) {
      const int m = sub*6 + ol;
      if (m < 81) {
        const float* wrow = (m < NMEL) ? (proj_w + (size_t)m*(HH+EE)) : stop_w;
        const f4* w4 = (const f4*)wrow;
        const f4* s4 = (const f4*)s_dec;
        float a2 = 0.0f;
        #pragma unroll
        for (int i = 0; i < 12; ++i) a2 += dot4(s4[kq + 32*i], w4[kq + 32*i]);
        a2 = red32(a2);
        if (kq == 0) {
          if (m < NMEL) out[(b_grp*TD + (TD-1))*NMEL + m] = a2 + proj_b[m];
          else          out[NB*TD*NMEL + b_grp*TD + (TD-1)] = a2 + stop_b[0];
        }
      }
    }
  }
}

extern "C" void kernel_launch(void* const* d_in, const int* in_sizes, int n_in,
                              void* d_out, int out_size, void* d_ws, size_t ws_size,
                              hipStream_t stream) {
  (void)in_sizes; (void)n_in; (void)out_size; (void)ws_size;
  const float* enc         = (const float*)d_in[0];
  const float* mels        = (const float*)d_in[1];
  const float* enc_proj_w  = (const float*)d_in[2];
  const float* lstm_proj_w = (const float*)d_in[3];
  const float* loc_conv_w  = (const float*)d_in[4];
  const float* loc_conv_b  = (const float*)d_in[5];
  const float* loc_dense_w = (const float*)d_in[6];
  const float* loc_dense_b = (const float*)d_in[7];
  const float* e_w         = (const float*)d_in[8];
  const float* e_b         = (const float*)d_in[9];
  const float* prenet1_w   = (const float*)d_in[10];
  const float* prenet2_w   = (const float*)d_in[11];
  const float* w_ih0       = (const float*)d_in[12];
  const float* b_ih0       = (const float*)d_in[14];
  const float* b_hh0       = (const float*)d_in[15];
  const float* w_ih1       = (const float*)d_in[16];
  const float* b_ih1       = (const float*)d_in[18];
  const float* b_hh1       = (const float*)d_in[19];
  const float* proj_w      = (const float*)d_in[20];
  const float* proj_b      = (const float*)d_in[21];
  const float* stop_w      = (const float*)d_in[22];
  const float* stop_b      = (const float*)d_in[23];
  const int*   text_len    = (const int*)d_in[24];
  float* ws  = (float*)d_ws;
  float* out = (float*)d_out;

  static int attr_set = 0;
  if (!attr_set) {
    hipFuncSetAttribute((const void*)k_main,
                        hipFuncAttributeMaxDynamicSharedMemorySize, DYN_BYTES);
    attr_set = 1;
  }

  k_init<<<dim3(32), dim3(256), 0, stream>>>(ws);
  k_prenet<<<dim3(TD*NB), dim3(256), 0, stream>>>(mels, prenet1_w, prenet2_w, ws);
  k_procenc<<<dim3(NB*TE), dim3(128), 0, stream>>>(enc, enc_proj_w, ws + OFF_PE);

  k_main<<<dim3(256), dim3(512), DYN_BYTES, stream>>>(
      enc, lstm_proj_w, loc_conv_w, loc_conv_b, loc_dense_w, loc_dense_b,
      e_w, e_b, w_ih0, b_ih0, b_hh0, w_ih1, b_ih1, b_hh1,
      proj_w, proj_b, stop_w, stop_b, text_len, ws, out);
}